// Round 18
// baseline (244.541 us; speedup 1.0000x reference)
//
#include <hip/hip_runtime.h>
#include <hip/hip_bf16.h>

#define B_   4
#define C_   256
#define N_   4096   // H*W
#define NH_  4
#define HD_  64
#define G_   32
#define CPG_ 8      // C_/G_
#define EPS_ 1e-5f

typedef __bf16 bf16x8 __attribute__((ext_vector_type(8)));
typedef __bf16 bf16x4 __attribute__((ext_vector_type(4)));
typedef float  f32x4  __attribute__((ext_vector_type(4)));
typedef unsigned int u32x4 __attribute__((ext_vector_type(4)));
typedef unsigned int u32x2 __attribute__((ext_vector_type(2)));

#define EXP2F(x) __builtin_amdgcn_exp2f(x)   // v_exp_f32: D = 2^S0

static __device__ __forceinline__ unsigned int packbf(float a, float b) {
    __bf16 x = (__bf16)a, y = (__bf16)b;
    unsigned short ux = __builtin_bit_cast(unsigned short, x);
    unsigned short uy = __builtin_bit_cast(unsigned short, y);
    return (unsigned int)ux | ((unsigned int)uy << 16);
}

// ---------------- W pre-conversion: f32 [m][c] -> bf16 [m][c], all 4 matrices ----
__global__ __launch_bounds__(256) void wconv_kernel(const float* __restrict__ w0,
                                                    const float* __restrict__ w1,
                                                    const float* __restrict__ w2,
                                                    const float* __restrict__ w3,
                                                    __bf16* __restrict__ dst) {
    const float* srcs[4] = {w0, w1, w2, w3};
    const float* s = srcs[blockIdx.y];
    __bf16* d = dst + (size_t)blockIdx.y * C_ * C_;
    const int i = blockIdx.x * 256 + threadIdx.x;
    float4 v = ((const float4*)s)[i];
    bf16x4 o;
    o[0] = (__bf16)v.x; o[1] = (__bf16)v.y; o[2] = (__bf16)v.z; o[3] = (__bf16)v.w;
    ((bf16x4*)d)[i] = o;
}

// ---------------- GN stats: 1024 threads -----------------------------------------
__global__ __launch_bounds__(1024) void gn_stats_kernel(const float* __restrict__ in0,
                                                        const float* __restrict__ in1,
                                                        const float* __restrict__ gw0,
                                                        const float* __restrict__ gb0,
                                                        const float* __restrict__ gw1,
                                                        const float* __restrict__ gb1,
                                                        float* __restrict__ stat) {
    const int which = blockIdx.y;
    const float* in = which ? in1 : in0;
    const float* gw = which ? gw1 : gw0;
    const float* gb = which ? gb1 : gb0;
    const int b = blockIdx.x / G_;
    const int g = blockIdx.x % G_;
    const int tid = threadIdx.x;
    const size_t base = ((size_t)b * C_ + g * CPG_) * N_;
    const float4* pv = (const float4*)(in + base);
    const int NC = (CPG_ * N_) / 4;

    float s = 0.f, ss = 0.f;
    #pragma unroll
    for (int i = tid; i < NC; i += 1024) {
        float4 v = pv[i];
        s  += v.x + v.y + v.z + v.w;
        ss += v.x * v.x + v.y * v.y + v.z * v.z + v.w * v.w;
    }
    #pragma unroll
    for (int m = 32; m >= 1; m >>= 1) { s += __shfl_xor(s, m); ss += __shfl_xor(ss, m); }
    __shared__ float red[32];
    const int w = tid >> 6;
    if ((tid & 63) == 0) { red[w] = s; red[16 + w] = ss; }
    __syncthreads();
    s = 0.f; ss = 0.f;
    #pragma unroll
    for (int i = 0; i < 16; i++) { s += red[i]; ss += red[16 + i]; }
    const float mean = s * (1.f / 32768.f);
    const float var  = ss * (1.f / 32768.f) - mean * mean;
    const float rinv = rsqrtf(var + EPS_);
    if (tid < CPG_) {
        const int c = g * CPG_ + tid;
        float* sp = stat + (size_t)which * 2 * B_ * C_;
        const float sc = rinv * gw[c];
        sp[b * C_ + c] = sc;
        sp[B_ * C_ + b * C_ + c] = gb[c] - mean * sc;
    }
}

// ---------------- GN normalize+transpose: fp32 [c][n] -> bf16 [n][c], coalesced --
__global__ __launch_bounds__(256, 4) void gn_norm_kernel(const float* __restrict__ in0,
                                                         const float* __restrict__ in1,
                                                         const float* __restrict__ stat,
                                                         __bf16* __restrict__ out0,
                                                         __bf16* __restrict__ out1) {
    const int which = blockIdx.z;
    const float* in = which ? in1 : in0;
    __bf16* out = which ? out1 : out0;
    const int n0 = blockIdx.x * 64;
    const int b  = blockIdx.y;
    const int tid = threadIdx.x;
    const int w = tid >> 6, lane = tid & 63;
    const float* scp = stat + (size_t)which * 2 * B_ * C_ + b * C_;
    const float* shp = scp + B_ * C_;

    __shared__ __bf16 Lt[64][264];   // [n][c+pad], c stored at chunk (c>>3)^(n>>3)

    #pragma unroll 16
    for (int p = 0; p < 64; p++) {
        const int c = p * 4 + w;                       // wave-uniform channel
        const float v = in[((size_t)(b * C_ + c)) * N_ + n0 + lane];
        const float o = v * scp[c] + shp[c];
        const int ch = (((c >> 3) ^ (lane >> 3)) << 3) + (c & 7);
        Lt[lane][ch] = (__bf16)o;
    }
    __syncthreads();
    #pragma unroll
    for (int q = 0; q < 8; q++) {
        const int r = q * 8 + (tid >> 5);
        const int l = tid & 31;
        const int ch = (l ^ (r >> 3)) << 3;
        *(bf16x8*)(out + ((size_t)b * N_ + n0 + r) * C_ + l * 8) =
            *(const bf16x8*)(&Lt[r][ch]);
    }
}

// ---------------- fused QKV GEMM: W-stationary in LDS ----------------------------
__global__ __launch_bounds__(256, 2) void qkv_kernel(const __bf16* __restrict__ Wall,
                                                     const float* __restrict__ bq,
                                                     const float* __restrict__ bk,
                                                     const float* __restrict__ bv,
                                                     const __bf16* __restrict__ Xq,   // [b][n][c]
                                                     const __bf16* __restrict__ Xkv,  // [b][n][c]
                                                     __bf16* __restrict__ Qo,  // [16][N][64]
                                                     __bf16* __restrict__ Ko,  // [16][N][64]
                                                     __bf16* __restrict__ Vo,  // [4][256][N]
                                                     float qscale) {
    const int n0 = blockIdx.x * 64;
    const int sel = blockIdx.y >> 1;                 // 0=Q 1=K 2=V
    const int m0 = (blockIdx.y & 1) * 128;
    const int b  = blockIdx.z;
    const int tid = threadIdx.x;
    const int w = tid >> 6, lane = tid & 63, quad = lane >> 4, l16 = lane & 15;
    const int wn = (w >> 1) * 32;
    const int wm = (w & 1) * 64;

    const __bf16* Wb   = Wall + (size_t)sel * C_ * C_;
    const __bf16* XT   = (sel == 0) ? Xq : Xkv;
    const float*  bias = (sel == 0) ? bq : ((sel == 1) ? bk : bv);
    const float   psc  = (sel == 0) ? qscale : 1.0f;

    __shared__ union {
        __bf16 Wl[128][264];
        __bf16 T1[64][136];
        __bf16 Tv[128][72];
    } sm;

    const __bf16* wsrc = Wb + (size_t)m0 * C_;
    #pragma unroll
    for (int i = 0; i < 16; i++) {
        const int e = i * 256 + tid;
        const int row = e >> 5;
        const int c8 = (e & 31) * 8;
        *(bf16x8*)(&sm.Wl[row][c8]) = *(const bf16x8*)(wsrc + (size_t)row * C_ + c8);
    }

    const __bf16* ap0 = XT + ((size_t)b * N_ + n0 + wn + l16) * C_ + quad * 8;
    const __bf16* ap1 = ap0 + (size_t)16 * C_;
    bf16x8 areg[2][8];
    #pragma unroll
    for (int ks = 0; ks < 8; ks++) {
        areg[0][ks] = *(const bf16x8*)(ap0 + ks * 32);
        areg[1][ks] = *(const bf16x8*)(ap1 + ks * 32);
    }

    f32x4 acc[2][4];
    #pragma unroll
    for (int qg = 0; qg < 2; qg++)
        #pragma unroll
        for (int jm = 0; jm < 4; jm++) acc[qg][jm] = (f32x4){0.f, 0.f, 0.f, 0.f};

    __syncthreads();

    #pragma unroll
    for (int ks = 0; ks < 8; ks++) {
        const int kc = ks * 32;
        #pragma unroll
        for (int jm = 0; jm < 4; jm++) {
            bf16x8 bw = *(const bf16x8*)(&sm.Wl[wm + jm * 16 + l16][kc + quad * 8]);
            acc[0][jm] = __builtin_amdgcn_mfma_f32_16x16x32_bf16(areg[0][ks], bw, acc[0][jm], 0, 0, 0);
            acc[1][jm] = __builtin_amdgcn_mfma_f32_16x16x32_bf16(areg[1][ks], bw, acc[1][jm], 0, 0, 0);
        }
    }

    if (sel == 2) {                               // V: [c][n] via LDS transpose
        __syncthreads();
        #pragma unroll
        for (int qg = 0; qg < 2; qg++)
            #pragma unroll
            for (int jm = 0; jm < 4; jm++) {
                const int mm = wm + jm * 16 + l16;
                const int nn = wn + qg * 16 + quad * 4;
                const float bi = bias[m0 + mm];
                bf16x4 o;
                #pragma unroll
                for (int r = 0; r < 4; r++) o[r] = (__bf16)(acc[qg][jm][r] + bi);
                *(bf16x4*)(&sm.Tv[mm][nn]) = o;
            }
        __syncthreads();
        #pragma unroll
        for (int i = 0; i < 4; i++) {
            const int mrow = i * 32 + (tid >> 3);
            const int ch = (tid & 7) * 8;
            *(bf16x8*)(Vo + (size_t)(b * C_ + m0 + mrow) * N_ + n0 + ch) =
                *(const bf16x8*)(&sm.Tv[mrow][ch]);
        }
    } else {                                      // Q/K: bf16 [bh][n][d]
        __bf16* OUTb = (sel == 0) ? Qo : Ko;
        __syncthreads();
        #pragma unroll
        for (int qg = 0; qg < 2; qg++)
            #pragma unroll
            for (int jm = 0; jm < 4; jm++) {
                const int m = m0 + wm + jm * 16 + l16;
                const float bi = bias[m];
                #pragma unroll
                for (int r = 0; r < 4; r++)
                    sm.T1[wn + qg * 16 + quad * 4 + r][wm + jm * 16 + l16] =
                        (__bf16)((acc[qg][jm][r] + bi) * psc);
            }
        __syncthreads();
        const int h0 = m0 >> 6;
        #pragma unroll
        for (int i = 0; i < 4; i++) {
            const int idx = i * 256 + tid;
            const int row = idx >> 4;
            const int c = (idx & 15) * 8;
            const int hh = h0 + (c >> 6);
            const int d = c & 63;
            *(bf16x8*)(OUTb + ((size_t)(b * NH_ + hh) * N_ + n0 + row) * HD_ + d) =
                *(const bf16x8*)(&sm.T1[row][c]);
        }
    }
}

// ---------------- final GEMM (Wo + residual): coalesced epilogue -----------------
__global__ __launch_bounds__(256, 2) void gemm_kernel(const __bf16* __restrict__ Wb,
                                                      const float* __restrict__ bias,
                                                      const __bf16* __restrict__ XT,
                                                      float* __restrict__ OUTf,
                                                      const float* __restrict__ RES) {
    const int n0 = blockIdx.x * 64;
    const int m0 = blockIdx.y * 128;
    const int b  = blockIdx.z;
    const int tid = threadIdx.x;
    const int w = tid >> 6, lane = tid & 63, quad = lane >> 4, l16 = lane & 15;
    const int wn = (w >> 1) * 32;
    const int wm = (w & 1) * 64;

    __shared__ union {
        __bf16 Wl[128][264];
        float  Tf[128][68];
    } sm;

    const __bf16* wsrc = Wb + (size_t)m0 * C_;
    #pragma unroll
    for (int i = 0; i < 16; i++) {
        const int e = i * 256 + tid;
        const int row = e >> 5;
        const int c8 = (e & 31) * 8;
        *(bf16x8*)(&sm.Wl[row][c8]) = *(const bf16x8*)(wsrc + (size_t)row * C_ + c8);
    }

    const __bf16* ap0 = XT + ((size_t)b * N_ + n0 + wn + l16) * C_ + quad * 8;
    const __bf16* ap1 = ap0 + (size_t)16 * C_;
    bf16x8 areg[2][8];
    #pragma unroll
    for (int ks = 0; ks < 8; ks++) {
        areg[0][ks] = *(const bf16x8*)(ap0 + ks * 32);
        areg[1][ks] = *(const bf16x8*)(ap1 + ks * 32);
    }

    f32x4 acc[2][4];
    #pragma unroll
    for (int qg = 0; qg < 2; qg++)
        #pragma unroll
        for (int jm = 0; jm < 4; jm++) acc[qg][jm] = (f32x4){0.f, 0.f, 0.f, 0.f};

    __syncthreads();

    #pragma unroll
    for (int ks = 0; ks < 8; ks++) {
        const int kc = ks * 32;
        #pragma unroll
        for (int jm = 0; jm < 4; jm++) {
            bf16x8 bw = *(const bf16x8*)(&sm.Wl[wm + jm * 16 + l16][kc + quad * 8]);
            acc[0][jm] = __builtin_amdgcn_mfma_f32_16x16x32_bf16(areg[0][ks], bw, acc[0][jm], 0, 0, 0);
            acc[1][jm] = __builtin_amdgcn_mfma_f32_16x16x32_bf16(areg[1][ks], bw, acc[1][jm], 0, 0, 0);
        }
    }

    __syncthreads();
    #pragma unroll
    for (int qg = 0; qg < 2; qg++)
        #pragma unroll
        for (int jm = 0; jm < 4; jm++) {
            const int mm = wm + jm * 16 + l16;
            const int nn = wn + qg * 16 + quad * 4;
            const float bi = bias[m0 + mm];
            f32x4 o;
            #pragma unroll
            for (int r = 0; r < 4; r++) o[r] = acc[qg][jm][r] + bi;
            *(f32x4*)(&sm.Tf[mm][nn]) = o;
        }
    __syncthreads();
    #pragma unroll
    for (int qp = 0; qp < 8; qp++) {
        const int mrow = qp * 16 + (tid >> 4);
        const int k4 = (tid & 15) * 4;
        const size_t off = (size_t)(b * C_ + mrow + m0) * N_ + n0 + k4;
        const float4 res = *(const float4*)(RES + off);
        f32x4 v = *(const f32x4*)(&sm.Tf[mrow][k4]);
        v[0] += res.x; v[1] += res.y; v[2] += res.z; v[3] += res.w;
        *(f32x4*)(OUTf + off) = v;
    }
}

// ---------------- Flash attention v9: split-KV (2 halves), 4 blocks/CU -----------
// Rescale-free softmax (p=exp2(s), no running max) makes KV-splitting exact:
// each half writes unnormalized bf16 partial O + per-row lsum; combiner divides
// by (l0+l1). Grid 1024 blocks -> 4 blocks/CU -> 4 waves/SIMD (was 2): the
// latency-hiding the 18%-occupancy / no-pipe-above-54% counters called for.
__global__ __launch_bounds__(256, 4) void attn_kernel(const __bf16* __restrict__ qT,  // [16][N][64], scale*log2e folded
                                                      const __bf16* __restrict__ kT,  // [16][N][64]
                                                      const __bf16* __restrict__ V,   // [4][256][N]
                                                      __bf16* __restrict__ Op,        // [2][16][N][64] partial
                                                      float* __restrict__ Ls) {       // [2][16][N]
    const int flat = blockIdx.y * 32 + blockIdx.x;
    const int bh = flat & 15;              // XCD = flat%8 = bh%8 (unchanged mapping)
    const int qt = (flat >> 4) & 31;
    const int half = flat >> 9;            // KV half
    const int q0 = qt * 128;
    const int kv0 = half * 2048;
    const int b = bh >> 2, h = bh & 3;
    const int tid = threadIdx.x;
    const int w = tid >> 6, lane = tid & 63, quad = lane >> 4, l16 = lane & 15;

    __shared__ union SMem {
        struct { __bf16 K[2][64][72]; __bf16 Vt[2][64][72]; } kv;
        __bf16 Ot[128][72];
    } sm;

    const __bf16* qTb = qT + (size_t)bh * N_ * HD_;
    const __bf16* kTb = kT + (size_t)bh * N_ * HD_;
    const __bf16* Vb  = V + ((size_t)b * C_ + h * HD_) * N_;

    bf16x8 qa[2][2];
    #pragma unroll
    for (int qg = 0; qg < 2; qg++)
        #pragma unroll
        for (int kk = 0; kk < 2; kk++)
            qa[qg][kk] = *(const bf16x8*)(qTb + (size_t)(q0 + w * 32 + qg * 16 + l16) * HD_ + kk * 32 + quad * 8);

    f32x4 oacc[2][4];
    #pragma unroll
    for (int qg = 0; qg < 2; qg++)
        #pragma unroll
        for (int j = 0; j < 4; j++) oacc[qg][j] = (f32x4){0.f, 0.f, 0.f, 0.f};
    float lsum[2] = {0.f, 0.f};

    const int srow = tid >> 3;
    const int scol = (tid & 7) * 8;

    bf16x8 rk[2], rv[2];
    #pragma unroll
    for (int i = 0; i < 2; i++) {
        const int row = srow + i * 32;
        rk[i] = *(const bf16x8*)(kTb + (size_t)(kv0 + row) * HD_ + scol);
        rv[i] = *(const bf16x8*)(Vb + (size_t)row * N_ + kv0 + scol);
    }

    for (int it = 0; it < 32; it++) {
        const int cur = it & 1;
        const int nm0 = kv0 + (((it + 1) * 64) & 2047);   // wraps within half (harmless reload)
        #pragma unroll
        for (int i = 0; i < 2; i++) {
            const int row = srow + i * 32;
            *(bf16x8*)(&sm.kv.K[cur][row][scol])  = rk[i];
            *(bf16x8*)(&sm.kv.Vt[cur][row][scol]) = rv[i];
        }
        #pragma unroll
        for (int i = 0; i < 2; i++) {
            const int row = srow + i * 32;
            rk[i] = *(const bf16x8*)(kTb + (size_t)(nm0 + row) * HD_ + scol);
            rv[i] = *(const bf16x8*)(Vb + (size_t)row * N_ + nm0 + scol);
        }
        asm volatile("s_waitcnt lgkmcnt(0)" ::: "memory");
        __builtin_amdgcn_s_barrier();
        bf16x8 kb[2][4], vb[2][4];
        #pragma unroll
        for (int kk = 0; kk < 2; kk++)
            #pragma unroll
            for (int j = 0; j < 4; j++) {
                kb[kk][j] = *(const bf16x8*)(&sm.kv.K[cur][j * 16 + l16][kk * 32 + quad * 8]);
                vb[kk][j] = *(const bf16x8*)(&sm.kv.Vt[cur][j * 16 + l16][kk * 32 + quad * 8]);
            }
        #pragma unroll
        for (int qg = 0; qg < 2; qg++) {
            f32x4 s[4];
            #pragma unroll
            for (int j = 0; j < 4; j++) s[j] = (f32x4){0.f, 0.f, 0.f, 0.f};
            #pragma unroll
            for (int kk = 0; kk < 2; kk++)
                #pragma unroll
                for (int j = 0; j < 4; j++)
                    s[j] = __builtin_amdgcn_mfma_f32_16x16x32_bf16(kb[kk][j], qa[qg][kk], s[j], 0, 0, 0);
            float p[4][4];
            float ls = 0.f;
            #pragma unroll
            for (int j = 0; j < 4; j++) {
                #pragma unroll
                for (int r = 0; r < 4; r++) p[j][r] = EXP2F(s[j][r]);
                ls += (p[j][0] + p[j][1]) + (p[j][2] + p[j][3]);
            }
            lsum[qg] += ls;
            unsigned int pk0[4], pk1[4];
            #pragma unroll
            for (int j = 0; j < 4; j++) {
                pk0[j] = packbf(p[j][0], p[j][1]);
                pk1[j] = packbf(p[j][2], p[j][3]);
            }
            #pragma unroll
            for (int kk = 0; kk < 2; kk++) {
                u32x2 t0 = __builtin_amdgcn_permlane32_swap(pk0[2 * kk], pk0[2 * kk + 1], false, false);
                u32x2 t1 = __builtin_amdgcn_permlane32_swap(pk1[2 * kk], pk1[2 * kk + 1], false, false);
                u32x2 a0 = __builtin_amdgcn_permlane16_swap(t0[0], t0[1], false, false);
                u32x2 a1 = __builtin_amdgcn_permlane16_swap(t1[0], t1[1], false, false);
                bf16x8 pb = __builtin_bit_cast(bf16x8, (u32x4){a0[0], a1[0], a0[1], a1[1]});
                #pragma unroll
                for (int jd = 0; jd < 4; jd++)
                    oacc[qg][jd] = __builtin_amdgcn_mfma_f32_16x16x32_bf16(vb[kk][jd], pb, oacc[qg][jd], 0, 0, 0);
            }
        }
    }
    // per-row partial denominators (cross-quad reduce); store, don't divide
    #pragma unroll
    for (int qg = 0; qg < 2; qg++) {
        float l = lsum[qg];
        l += __shfl_xor(l, 16);
        l += __shfl_xor(l, 32);
        if (quad == 0)
            Ls[(size_t)(half * 16 + bh) * N_ + q0 + w * 32 + qg * 16 + l16] = l;
    }
    __syncthreads();   // all kv reads done before Ot overwrites the union
    #pragma unroll
    for (int qg = 0; qg < 2; qg++) {
        #pragma unroll
        for (int jd = 0; jd < 4; jd++) {
            bf16x4 o;
            #pragma unroll
            for (int r = 0; r < 4; r++) o[r] = (__bf16)(oacc[qg][jd][r]);   // unnormalized
            *(bf16x4*)(&sm.Ot[w * 32 + qg * 16 + l16][jd * 16 + quad * 4]) = o;
        }
    }
    __syncthreads();
    // store partial O [half][bh][q][d], 64-d rows = 128B contiguous
    __bf16* Ob = Op + ((size_t)(half * 16 + bh) * N_ + q0) * HD_;
    const int row0 = tid >> 3, chh = (tid & 7) * 8;
    #pragma unroll
    for (int i = 0; i < 4; i++) {
        const int row = row0 + i * 32;
        *(bf16x8*)(Ob + (size_t)row * HD_ + chh) = *(const bf16x8*)(&sm.Ot[row][chh]);
    }
}

// ---------------- attn combine: O = (O0+O1)/(l0+l1) -> attno [b][n][c] -----------
__global__ __launch_bounds__(256) void attn_combine_kernel(const __bf16* __restrict__ Op,
                                                           const float* __restrict__ Ls,
                                                           __bf16* __restrict__ O) {
    const int q0 = blockIdx.x * 64;
    const int bh = blockIdx.y;
    const int b = bh >> 2, h = bh & 3;
    const int tid = threadIdx.x;
    const __bf16* O0 = Op + ((size_t)bh * N_ + q0) * HD_;
    const __bf16* O1 = Op + ((size_t)(16 + bh) * N_ + q0) * HD_;
    const float* L0 = Ls + (size_t)bh * N_ + q0;
    const float* L1 = Ls + (size_t)(16 + bh) * N_ + q0;
    #pragma unroll
    for (int i = 0; i < 2; i++) {
        const int u = i * 256 + tid;          // 512 units x 8 elems = 64q x 64d
        const int row = u >> 3, dc = (u & 7) * 8;
        bf16x8 a = *(const bf16x8*)(O0 + (size_t)row * HD_ + dc);
        bf16x8 c = *(const bf16x8*)(O1 + (size_t)row * HD_ + dc);
        const float inv = 1.f / (L0[row] + L1[row]);
        bf16x8 o;
        #pragma unroll
        for (int j = 0; j < 8; j++)
            o[j] = (__bf16)(((float)a[j] + (float)c[j]) * inv);
        *(bf16x8*)(O + ((size_t)b * N_ + q0 + row) * C_ + h * HD_ + dc) = o;
    }
}

extern "C" void kernel_launch(void* const* d_in, const int* in_sizes, int n_in,
                              void* d_out, int out_size, void* d_ws, size_t ws_size,
                              hipStream_t stream) {
    const float* x     = (const float*)d_in[0];
    const float* cond  = (const float*)d_in[1];
    const float* gnqw  = (const float*)d_in[2];
    const float* gnqb  = (const float*)d_in[3];
    const float* gnkw  = (const float*)d_in[4];
    const float* gnkb  = (const float*)d_in[5];
    const float* wq    = (const float*)d_in[6];
    const float* bq    = (const float*)d_in[7];
    const float* wk    = (const float*)d_in[8];
    const float* bk    = (const float*)d_in[9];
    const float* wv    = (const float*)d_in[10];
    const float* bv    = (const float*)d_in[11];
    const float* wo    = (const float*)d_in[12];
    const float* bo    = (const float*)d_in[13];
    float* out = (float*)d_out;

    const size_t TEN = (size_t)B_ * C_ * N_;
    const size_t WSZ = (size_t)C_ * C_;
    __bf16* gnx   = (__bf16*)d_ws;      // [b][n][c]  (reused as Opart after qkv)
    __bf16* gnc   = gnx + TEN;          // [b][n][c]  (reused as Opart after qkv)
    __bf16* qT    = gnc + TEN;          // [bh][n][d]
    __bf16* kT    = qT  + TEN;          // [bh][n][d]
    __bf16* v     = kT  + TEN;          // [b][c][n]
    __bf16* attno = v   + TEN;          // [b][n][c]
    __bf16* wb    = attno + TEN;        // 4x [256][256] bf16 (q,k,v,o)
    float*  stat  = (float*)(wb + 4 * WSZ);   // [2][2][B][C] f32
    float*  lsum  = stat + 2 * 2 * B_ * C_;   // [2][16][N] f32 (512KB)
    __bf16* opart = gnx;                // [2][16][N][64] bf16 = 16MB, overlays gnx+gnc

    wconv_kernel<<<dim3(64, 4), 256, 0, stream>>>(wq, wk, wv, wo, wb);

    gn_stats_kernel<<<dim3(B_ * G_, 2), 1024, 0, stream>>>(x, cond, gnqw, gnqb, gnkw, gnkb, stat);
    gn_norm_kernel<<<dim3(N_ / 64, B_, 2), 256, 0, stream>>>(x, cond, stat, gnx, gnc);

    qkv_kernel<<<dim3(N_ / 64, 6, B_), 256, 0, stream>>>(wb, bq, bk, bv, gnx, gnc,
                                                         qT, kT, v,
                                                         0.125f * 1.44269504088896f);

    attn_kernel<<<dim3(32, 32), 256, 0, stream>>>(qT, kT, v, opart, lsum);
    attn_combine_kernel<<<dim3(N_ / 64, 16), 256, 0, stream>>>(opart, lsum, attno);

    gemm_kernel<<<dim3(N_ / 64, C_ / 128, B_), 256, 0, stream>>>(wb + 3 * WSZ, bo, attno, out, x);
}

// Round 20
// 238.838 us; speedup vs baseline: 1.0239x; 1.0239x over previous
//
#include <hip/hip_runtime.h>
#include <hip/hip_bf16.h>

#define B_   4
#define C_   256
#define N_   4096   // H*W
#define NH_  4
#define HD_  64
#define G_   32
#define CPG_ 8      // C_/G_
#define EPS_ 1e-5f

typedef __bf16 bf16x8 __attribute__((ext_vector_type(8)));
typedef __bf16 bf16x4 __attribute__((ext_vector_type(4)));
typedef float  f32x4  __attribute__((ext_vector_type(4)));
typedef unsigned int u32x4 __attribute__((ext_vector_type(4)));
typedef unsigned int u32x2 __attribute__((ext_vector_type(2)));

#define EXP2F(x) __builtin_amdgcn_exp2f(x)   // v_exp_f32: D = 2^S0

static __device__ __forceinline__ unsigned int packbf(float a, float b) {
    __bf16 x = (__bf16)a, y = (__bf16)b;
    unsigned short ux = __builtin_bit_cast(unsigned short, x);
    unsigned short uy = __builtin_bit_cast(unsigned short, y);
    return (unsigned int)ux | ((unsigned int)uy << 16);
}

// ---------------- W pre-conversion: f32 [m][c] -> bf16 [m][c], all 4 matrices ----
__global__ __launch_bounds__(256) void wconv_kernel(const float* __restrict__ w0,
                                                    const float* __restrict__ w1,
                                                    const float* __restrict__ w2,
                                                    const float* __restrict__ w3,
                                                    __bf16* __restrict__ dst) {
    const float* srcs[4] = {w0, w1, w2, w3};
    const float* s = srcs[blockIdx.y];
    __bf16* d = dst + (size_t)blockIdx.y * C_ * C_;
    const int i = blockIdx.x * 256 + threadIdx.x;
    float4 v = ((const float4*)s)[i];
    bf16x4 o;
    o[0] = (__bf16)v.x; o[1] = (__bf16)v.y; o[2] = (__bf16)v.z; o[3] = (__bf16)v.w;
    ((bf16x4*)d)[i] = o;
}

// ---------------- GN stats: 1024 threads -----------------------------------------
__global__ __launch_bounds__(1024) void gn_stats_kernel(const float* __restrict__ in0,
                                                        const float* __restrict__ in1,
                                                        const float* __restrict__ gw0,
                                                        const float* __restrict__ gb0,
                                                        const float* __restrict__ gw1,
                                                        const float* __restrict__ gb1,
                                                        float* __restrict__ stat) {
    const int which = blockIdx.y;
    const float* in = which ? in1 : in0;
    const float* gw = which ? gw1 : gw0;
    const float* gb = which ? gb1 : gb0;
    const int b = blockIdx.x / G_;
    const int g = blockIdx.x % G_;
    const int tid = threadIdx.x;
    const size_t base = ((size_t)b * C_ + g * CPG_) * N_;
    const float4* pv = (const float4*)(in + base);
    const int NC = (CPG_ * N_) / 4;

    float s = 0.f, ss = 0.f;
    #pragma unroll
    for (int i = tid; i < NC; i += 1024) {
        float4 v = pv[i];
        s  += v.x + v.y + v.z + v.w;
        ss += v.x * v.x + v.y * v.y + v.z * v.z + v.w * v.w;
    }
    #pragma unroll
    for (int m = 32; m >= 1; m >>= 1) { s += __shfl_xor(s, m); ss += __shfl_xor(ss, m); }
    __shared__ float red[32];
    const int w = tid >> 6;
    if ((tid & 63) == 0) { red[w] = s; red[16 + w] = ss; }
    __syncthreads();
    s = 0.f; ss = 0.f;
    #pragma unroll
    for (int i = 0; i < 16; i++) { s += red[i]; ss += red[16 + i]; }
    const float mean = s * (1.f / 32768.f);
    const float var  = ss * (1.f / 32768.f) - mean * mean;
    const float rinv = rsqrtf(var + EPS_);
    if (tid < CPG_) {
        const int c = g * CPG_ + tid;
        float* sp = stat + (size_t)which * 2 * B_ * C_;
        const float sc = rinv * gw[c];
        sp[b * C_ + c] = sc;
        sp[B_ * C_ + b * C_ + c] = gb[c] - mean * sc;
    }
}

// ---------------- GN normalize+transpose: fp32 [c][n] -> bf16 [n][c], coalesced --
__global__ __launch_bounds__(256, 4) void gn_norm_kernel(const float* __restrict__ in0,
                                                         const float* __restrict__ in1,
                                                         const float* __restrict__ stat,
                                                         __bf16* __restrict__ out0,
                                                         __bf16* __restrict__ out1) {
    const int which = blockIdx.z;
    const float* in = which ? in1 : in0;
    __bf16* out = which ? out1 : out0;
    const int n0 = blockIdx.x * 64;
    const int b  = blockIdx.y;
    const int tid = threadIdx.x;
    const int w = tid >> 6, lane = tid & 63;
    const float* scp = stat + (size_t)which * 2 * B_ * C_ + b * C_;
    const float* shp = scp + B_ * C_;

    __shared__ __bf16 Lt[64][264];   // [n][c+pad], c stored at chunk (c>>3)^(n>>3)

    #pragma unroll 16
    for (int p = 0; p < 64; p++) {
        const int c = p * 4 + w;                       // wave-uniform channel
        const float v = in[((size_t)(b * C_ + c)) * N_ + n0 + lane];
        const float o = v * scp[c] + shp[c];
        const int ch = (((c >> 3) ^ (lane >> 3)) << 3) + (c & 7);
        Lt[lane][ch] = (__bf16)o;
    }
    __syncthreads();
    #pragma unroll
    for (int q = 0; q < 8; q++) {
        const int r = q * 8 + (tid >> 5);
        const int l = tid & 31;
        const int ch = (l ^ (r >> 3)) << 3;
        *(bf16x8*)(out + ((size_t)b * N_ + n0 + r) * C_ + l * 8) =
            *(const bf16x8*)(&Lt[r][ch]);
    }
}

// ---------------- fused QKV GEMM v3: BOTH X and W staged via coalesced LDS -------
// Old A-frag loads from XT [n][c] had 512B lane stride = 12.5% cache-line
// efficiency (the hidden non-attn bottleneck). Now X tile (64n x 256c = 32KB)
// and W tile (64m x 256c = 32KB) are staged with fully-coalesced row reads;
// fragments come from LDS (padded stride, bank-balanced b128 reads).
// blockIdx.y: sel = y>>2 (0=Q 1=K 2=V), mt = y&3 (m-tile of 64).
__global__ __launch_bounds__(256, 2) void qkv_kernel(const __bf16* __restrict__ Wall,
                                                     const float* __restrict__ bq,
                                                     const float* __restrict__ bk,
                                                     const float* __restrict__ bv,
                                                     const __bf16* __restrict__ Xq,   // [b][n][c]
                                                     const __bf16* __restrict__ Xkv,  // [b][n][c]
                                                     __bf16* __restrict__ Qo,  // [16][N][64]
                                                     __bf16* __restrict__ Ko,  // [16][N][64]
                                                     __bf16* __restrict__ Vo,  // [4][256][N]
                                                     float qscale) {
    const int n0 = blockIdx.x * 64;
    const int sel = blockIdx.y >> 2;                 // 0=Q 1=K 2=V
    const int mt  = blockIdx.y & 3;
    const int m0  = mt * 64;
    const int b   = blockIdx.z;
    const int tid = threadIdx.x;
    const int w = tid >> 6, lane = tid & 63, quad = lane >> 4, l16 = lane & 15;
    const int wn = (w >> 1) * 32;                    // wave n-offset (0/32)
    const int wm = (w & 1) * 32;                     // wave m-offset (0/32)

    const __bf16* Wb   = Wall + (size_t)sel * C_ * C_;
    const __bf16* XT   = (sel == 0) ? Xq : Xkv;
    const float*  bias = (sel == 0) ? bq : ((sel == 1) ? bk : bv);
    const float   psc  = (sel == 0) ? qscale : 1.0f;

    __shared__ union {
        struct { __bf16 Wl[64][264]; __bf16 Xl[64][264]; } s;   // 67.6 KB
        __bf16 T1[64][72];                                      // [n][m] epilogue
        __bf16 Tv[64][72];                                      // [m][n] epilogue
    } sm;

    // stage W rows m0..m0+64 and X rows n0..n0+64 (coalesced 16B/lane row reads)
    const __bf16* wsrc = Wb + (size_t)m0 * C_;
    const __bf16* xsrc = XT + ((size_t)b * N_ + n0) * C_;
    #pragma unroll
    for (int i = 0; i < 8; i++) {
        const int e = i * 256 + tid;                 // 2048 16B-units per array
        const int row = e >> 5;
        const int c8 = (e & 31) * 8;
        *(bf16x8*)(&sm.s.Wl[row][c8]) = *(const bf16x8*)(wsrc + (size_t)row * C_ + c8);
        *(bf16x8*)(&sm.s.Xl[row][c8]) = *(const bf16x8*)(xsrc + (size_t)row * C_ + c8);
    }

    f32x4 acc[2][2];
    #pragma unroll
    for (int qg = 0; qg < 2; qg++)
        #pragma unroll
        for (int jm = 0; jm < 2; jm++) acc[qg][jm] = (f32x4){0.f, 0.f, 0.f, 0.f};

    __syncthreads();

    #pragma unroll
    for (int ks = 0; ks < 8; ks++) {
        const int kc = ks * 32 + quad * 8;
        bf16x8 a0 = *(const bf16x8*)(&sm.s.Xl[wn + l16][kc]);
        bf16x8 a1 = *(const bf16x8*)(&sm.s.Xl[wn + 16 + l16][kc]);
        bf16x8 w0 = *(const bf16x8*)(&sm.s.Wl[wm + l16][kc]);
        bf16x8 w1 = *(const bf16x8*)(&sm.s.Wl[wm + 16 + l16][kc]);
        acc[0][0] = __builtin_amdgcn_mfma_f32_16x16x32_bf16(a0, w0, acc[0][0], 0, 0, 0);
        acc[0][1] = __builtin_amdgcn_mfma_f32_16x16x32_bf16(a0, w1, acc[0][1], 0, 0, 0);
        acc[1][0] = __builtin_amdgcn_mfma_f32_16x16x32_bf16(a1, w0, acc[1][0], 0, 0, 0);
        acc[1][1] = __builtin_amdgcn_mfma_f32_16x16x32_bf16(a1, w1, acc[1][1], 0, 0, 0);
    }

    __syncthreads();                                 // staging reads done before union overwrite
    if (sel == 2) {                                  // V: [c][n] via Tv[m][n]
        #pragma unroll
        for (int qg = 0; qg < 2; qg++)
            #pragma unroll
            for (int jm = 0; jm < 2; jm++) {
                const int mm = wm + jm * 16 + l16;
                const int nn = wn + qg * 16 + quad * 4;
                const float bi = bias[m0 + mm];
                bf16x4 o;
                #pragma unroll
                for (int r = 0; r < 4; r++) o[r] = (__bf16)(acc[qg][jm][r] + bi);
                *(bf16x4*)(&sm.Tv[mm][nn]) = o;
            }
        __syncthreads();
        #pragma unroll
        for (int i = 0; i < 2; i++) {
            const int e = i * 256 + tid;
            const int mrow = e >> 3, ch = (e & 7) * 8;
            *(bf16x8*)(Vo + (size_t)(b * C_ + m0 + mrow) * N_ + n0 + ch) =
                *(const bf16x8*)(&sm.Tv[mrow][ch]);
        }
    } else {                                         // Q/K: [bh][n][d], head = mt
        __bf16* OUTb = (sel == 0) ? Qo : Ko;
        #pragma unroll
        for (int qg = 0; qg < 2; qg++)
            #pragma unroll
            for (int jm = 0; jm < 2; jm++) {
                const int mm = wm + jm * 16 + l16;
                const float bi = bias[m0 + mm];
                #pragma unroll
                for (int r = 0; r < 4; r++)
                    sm.T1[wn + qg * 16 + quad * 4 + r][mm] = (__bf16)((acc[qg][jm][r] + bi) * psc);
            }
        __syncthreads();
        #pragma unroll
        for (int i = 0; i < 2; i++) {
            const int e = i * 256 + tid;
            const int row = e >> 3, ch = (e & 7) * 8;
            *(bf16x8*)(OUTb + ((size_t)(b * NH_ + mt) * N_ + n0 + row) * HD_ + ch) =
                *(const bf16x8*)(&sm.T1[row][ch]);
        }
    }
}

// ---------------- final GEMM v3 (Wo + residual): X and W both LDS-staged ---------
__global__ __launch_bounds__(256, 2) void gemm_kernel(const __bf16* __restrict__ Wb,
                                                      const float* __restrict__ bias,
                                                      const __bf16* __restrict__ XT,
                                                      float* __restrict__ OUTf,
                                                      const float* __restrict__ RES) {
    const int n0 = blockIdx.x * 64;
    const int m0 = blockIdx.y * 64;
    const int b  = blockIdx.z;
    const int tid = threadIdx.x;
    const int w = tid >> 6, lane = tid & 63, quad = lane >> 4, l16 = lane & 15;
    const int wn = (w >> 1) * 32;
    const int wm = (w & 1) * 32;

    __shared__ union {
        struct { __bf16 Wl[64][264]; __bf16 Xl[64][264]; } s;   // 67.6 KB
        float Tf[64][68];                                       // [m][n] f32 epilogue
    } sm;

    const __bf16* wsrc = Wb + (size_t)m0 * C_;
    const __bf16* xsrc = XT + ((size_t)b * N_ + n0) * C_;
    #pragma unroll
    for (int i = 0; i < 8; i++) {
        const int e = i * 256 + tid;
        const int row = e >> 5;
        const int c8 = (e & 31) * 8;
        *(bf16x8*)(&sm.s.Wl[row][c8]) = *(const bf16x8*)(wsrc + (size_t)row * C_ + c8);
        *(bf16x8*)(&sm.s.Xl[row][c8]) = *(const bf16x8*)(xsrc + (size_t)row * C_ + c8);
    }

    f32x4 acc[2][2];
    #pragma unroll
    for (int qg = 0; qg < 2; qg++)
        #pragma unroll
        for (int jm = 0; jm < 2; jm++) acc[qg][jm] = (f32x4){0.f, 0.f, 0.f, 0.f};

    __syncthreads();

    #pragma unroll
    for (int ks = 0; ks < 8; ks++) {
        const int kc = ks * 32 + quad * 8;
        bf16x8 a0 = *(const bf16x8*)(&sm.s.Xl[wn + l16][kc]);
        bf16x8 a1 = *(const bf16x8*)(&sm.s.Xl[wn + 16 + l16][kc]);
        bf16x8 w0 = *(const bf16x8*)(&sm.s.Wl[wm + l16][kc]);
        bf16x8 w1 = *(const bf16x8*)(&sm.s.Wl[wm + 16 + l16][kc]);
        acc[0][0] = __builtin_amdgcn_mfma_f32_16x16x32_bf16(a0, w0, acc[0][0], 0, 0, 0);
        acc[0][1] = __builtin_amdgcn_mfma_f32_16x16x32_bf16(a0, w1, acc[0][1], 0, 0, 0);
        acc[1][0] = __builtin_amdgcn_mfma_f32_16x16x32_bf16(a1, w0, acc[1][0], 0, 0, 0);
        acc[1][1] = __builtin_amdgcn_mfma_f32_16x16x32_bf16(a1, w1, acc[1][1], 0, 0, 0);
    }

    __syncthreads();
    #pragma unroll
    for (int qg = 0; qg < 2; qg++)
        #pragma unroll
        for (int jm = 0; jm < 2; jm++) {
            const int mm = wm + jm * 16 + l16;
            const int nn = wn + qg * 16 + quad * 4;
            const float bi = bias[m0 + mm];
            f32x4 o;
            #pragma unroll
            for (int r = 0; r < 4; r++) o[r] = acc[qg][jm][r] + bi;
            *(f32x4*)(&sm.Tf[mm][nn]) = o;
        }
    __syncthreads();
    #pragma unroll
    for (int qp = 0; qp < 4; qp++) {
        const int mrow = qp * 16 + (tid >> 4);
        const int k4 = (tid & 15) * 4;
        const size_t off = (size_t)(b * C_ + m0 + mrow) * N_ + n0 + k4;
        const float4 res = *(const float4*)(RES + off);
        f32x4 v = *(const f32x4*)(&sm.Tf[mrow][k4]);
        v[0] += res.x; v[1] += res.y; v[2] += res.z; v[3] += res.w;
        *(f32x4*)(OUTf + off) = v;
    }
}

// ---------------- Flash attention v8 (reverted R16 control) ----------------------
__global__ __launch_bounds__(256, 2) void attn_kernel(const __bf16* __restrict__ qT,  // [16][N][64], scale*log2e folded
                                                      const __bf16* __restrict__ kT,  // [16][N][64]
                                                      const __bf16* __restrict__ V,   // [4][256][N]
                                                      __bf16* __restrict__ O) {       // [4][N][256]
    const int flat = blockIdx.y * 32 + blockIdx.x;
    const int bh = flat & 15;
    const int qt = flat >> 4;
    const int q0 = qt * 128;
    const int b = bh >> 2, h = bh & 3;
    const int tid = threadIdx.x;
    const int w = tid >> 6, lane = tid & 63, quad = lane >> 4, l16 = lane & 15;

    __shared__ union SMem {
        struct { __bf16 K[2][64][72]; __bf16 Vt[2][64][72]; } kv;
        __bf16 Ot[128][72];
    } sm;

    const __bf16* qTb = qT + (size_t)bh * N_ * HD_;
    const __bf16* kTb = kT + (size_t)bh * N_ * HD_;
    const __bf16* Vb  = V + ((size_t)b * C_ + h * HD_) * N_;

    bf16x8 qa[2][2];
    #pragma unroll
    for (int qg = 0; qg < 2; qg++)
        #pragma unroll
        for (int kk = 0; kk < 2; kk++)
            qa[qg][kk] = *(const bf16x8*)(qTb + (size_t)(q0 + w * 32 + qg * 16 + l16) * HD_ + kk * 32 + quad * 8);

    f32x4 oacc[2][4];
    #pragma unroll
    for (int qg = 0; qg < 2; qg++)
        #pragma unroll
        for (int j = 0; j < 4; j++) oacc[qg][j] = (f32x4){0.f, 0.f, 0.f, 0.f};
    float lsum[2] = {0.f, 0.f};

    const int srow = tid >> 3;
    const int scol = (tid & 7) * 8;

    bf16x8 rk[2], rv[2];
    #pragma unroll
    for (int i = 0; i < 2; i++) {
        const int row = srow + i * 32;
        rk[i] = *(const bf16x8*)(kTb + (size_t)row * HD_ + scol);
        rv[i] = *(const bf16x8*)(Vb + (size_t)row * N_ + scol);
    }

    for (int it = 0; it < N_ / 64; it++) {
        const int cur = it & 1;
        const int nm0 = ((it + 1) * 64) & (N_ - 1);
        #pragma unroll
        for (int i = 0; i < 2; i++) {
            const int row = srow + i * 32;
            *(bf16x8*)(&sm.kv.K[cur][row][scol])  = rk[i];
            *(bf16x8*)(&sm.kv.Vt[cur][row][scol]) = rv[i];
        }
        #pragma unroll
        for (int i = 0; i < 2; i++) {
            const int row = srow + i * 32;
            rk[i] = *(const bf16x8*)(kTb + (size_t)(nm0 + row) * HD_ + scol);
            rv[i] = *(const bf16x8*)(Vb + (size_t)row * N_ + nm0 + scol);
        }
        asm volatile("s_waitcnt lgkmcnt(0)" ::: "memory");
        __builtin_amdgcn_s_barrier();
        bf16x8 kb[2][4], vb[2][4];
        #pragma unroll
        for (int kk = 0; kk < 2; kk++)
            #pragma unroll
            for (int j = 0; j < 4; j++) {
                kb[kk][j] = *(const bf16x8*)(&sm.kv.K[cur][j * 16 + l16][kk * 32 + quad * 8]);
                vb[kk][j] = *(const bf16x8*)(&sm.kv.Vt[cur][j * 16 + l16][kk * 32 + quad * 8]);
            }
        #pragma unroll
        for (int qg = 0; qg < 2; qg++) {
            f32x4 s[4];
            #pragma unroll
            for (int j = 0; j < 4; j++) s[j] = (f32x4){0.f, 0.f, 0.f, 0.f};
            #pragma unroll
            for (int kk = 0; kk < 2; kk++)
                #pragma unroll
                for (int j = 0; j < 4; j++)
                    s[j] = __builtin_amdgcn_mfma_f32_16x16x32_bf16(kb[kk][j], qa[qg][kk], s[j], 0, 0, 0);
            float p[4][4];
            float ls = 0.f;
            #pragma unroll
            for (int j = 0; j < 4; j++) {
                #pragma unroll
                for (int r = 0; r < 4; r++) p[j][r] = EXP2F(s[j][r]);
                ls += (p[j][0] + p[j][1]) + (p[j][2] + p[j][3]);
            }
            lsum[qg] += ls;
            unsigned int pk0[4], pk1[4];
            #pragma unroll
            for (int j = 0; j < 4; j++) {
                pk0[j] = packbf(p[j][0], p[j][1]);
                pk1[j] = packbf(p[j][2], p[j][3]);
            }
            #pragma unroll
            for (int kk = 0; kk < 2; kk++) {
                u32x2 t0 = __builtin_amdgcn_permlane32_swap(pk0[2 * kk], pk0[2 * kk + 1], false, false);
                u32x2 t1 = __builtin_amdgcn_permlane32_swap(pk1[2 * kk], pk1[2 * kk + 1], false, false);
                u32x2 a0 = __builtin_amdgcn_permlane16_swap(t0[0], t0[1], false, false);
                u32x2 a1 = __builtin_amdgcn_permlane16_swap(t1[0], t1[1], false, false);
                bf16x8 pb = __builtin_bit_cast(bf16x8, (u32x4){a0[0], a1[0], a0[1], a1[1]});
                #pragma unroll
                for (int jd = 0; jd < 4; jd++)
                    oacc[qg][jd] = __builtin_amdgcn_mfma_f32_16x16x32_bf16(vb[kk][jd], pb, oacc[qg][jd], 0, 0, 0);
            }
        }
    }
    float inv[2];
    #pragma unroll
    for (int qg = 0; qg < 2; qg++) {
        float l = lsum[qg];
        l += __shfl_xor(l, 16);
        l += __shfl_xor(l, 32);
        inv[qg] = 1.f / l;
    }
    __syncthreads();
    #pragma unroll
    for (int qg = 0; qg < 2; qg++) {
        #pragma unroll
        for (int jd = 0; jd < 4; jd++) {
            bf16x4 o;
            #pragma unroll
            for (int r = 0; r < 4; r++) o[r] = (__bf16)(oacc[qg][jd][r] * inv[qg]);
            *(bf16x4*)(&sm.Ot[w * 32 + qg * 16 + l16][jd * 16 + quad * 4]) = o;
        }
    }
    __syncthreads();
    __bf16* Ob = O + ((size_t)b * N_ + q0) * C_ + h * HD_;
    const int row0 = tid >> 3, chh = (tid & 7) * 8;
    #pragma unroll
    for (int i = 0; i < 4; i++) {
        const int row = row0 + i * 32;
        *(bf16x8*)(Ob + (size_t)row * C_ + chh) = *(const bf16x8*)(&sm.Ot[row][chh]);
    }
}

extern "C" void kernel_launch(void* const* d_in, const int* in_sizes, int n_in,
                              void* d_out, int out_size, void* d_ws, size_t ws_size,
                              hipStream_t stream) {
    const float* x     = (const float*)d_in[0];
    const float* cond  = (const float*)d_in[1];
    const float* gnqw  = (const float*)d_in[2];
    const float* gnqb  = (const float*)d_in[3];
    const float* gnkw  = (const float*)d_in[4];
    const float* gnkb  = (const float*)d_in[5];
    const float* wq    = (const float*)d_in[6];
    const float* bq    = (const float*)d_in[7];
    const float* wk    = (const float*)d_in[8];
    const float* bk    = (const float*)d_in[9];
    const float* wv    = (const float*)d_in[10];
    const float* bv    = (const float*)d_in[11];
    const float* wo    = (const float*)d_in[12];
    const float* bo    = (const float*)d_in[13];
    float* out = (float*)d_out;

    const size_t TEN = (size_t)B_ * C_ * N_;
    const size_t WSZ = (size_t)C_ * C_;
    __bf16* gnx   = (__bf16*)d_ws;      // [b][n][c]
    __bf16* gnc   = gnx + TEN;          // [b][n][c]
    __bf16* qT    = gnc + TEN;          // [bh][n][d]
    __bf16* kT    = qT  + TEN;          // [bh][n][d]
    __bf16* v     = kT  + TEN;          // [b][c][n]
    __bf16* attno = v   + TEN;          // [b][n][c]
    __bf16* wb    = attno + TEN;        // 4x [256][256] bf16 (q,k,v,o)
    float*  stat  = (float*)(wb + 4 * WSZ);   // [2][2][B][C] f32

    wconv_kernel<<<dim3(64, 4), 256, 0, stream>>>(wq, wk, wv, wo, wb);

    gn_stats_kernel<<<dim3(B_ * G_, 2), 1024, 0, stream>>>(x, cond, gnqw, gnqb, gnkw, gnkb, stat);
    gn_norm_kernel<<<dim3(N_ / 64, B_, 2), 256, 0, stream>>>(x, cond, stat, gnx, gnc);

    qkv_kernel<<<dim3(N_ / 64, 12, B_), 256, 0, stream>>>(wb, bq, bk, bv, gnx, gnc,
                                                          qT, kT, v,
                                                          0.125f * 1.44269504088896f);

    attn_kernel<<<dim3(32, 16), 256, 0, stream>>>(qT, kT, v, attno);

    gemm_kernel<<<dim3(N_ / 64, C_ / 64, B_), 256, 0, stream>>>(wb + 3 * WSZ, bo, attno, out, x);
}